// Round 13
// baseline (416.730 us; speedup 1.0000x reference)
//
#include <hip/hip_runtime.h>
#include <hip/hip_cooperative_groups.h>
#include <hip/hip_fp16.h>
#include <cstdint>

namespace cg = cooperative_groups;

// ---------------- CSR build: single cooperative kernel (R13) ----------------
// R12 ledger: ~65us of the 229 was inter-kernel launch gaps (9 dispatches).
// Fuse the 5 build kernels into one cooperative kernel; grid.sync() between
// phases (~1-2us) replaces ~7us launch gaps. Grid = 196 blocks = NBb = NBUCK,
// LDS 39KB -> all blocks co-resident on 256 CUs.

#define EPBH 8192   // edges per block in hist/scatter phases (256 thr x 32)
#define DCAP 9216   // LDS staging capacity in csr phase (mean ~8163 edges)

__global__ __launch_bounds__(256) void build_csr_coop(
    const int* __restrict__ src, const int* __restrict__ dst,
    int* __restrict__ hist,      // [nbuck][nb]; in-place becomes within-bucket excl prefix
    int* __restrict__ bt,        // [nbuck] bucket totals
    int* __restrict__ bko,       // [nbuck+1] bucket offsets
    int* __restrict__ row_ptr, float* __restrict__ dinv,
    int* __restrict__ col, uint32_t* __restrict__ ebuf,
    int ne, int nb, int nbuck, int n) {
  cg::grid_group grid = cg::this_grid();
  __shared__ int lh[256];
  __shared__ int ls[256];
  __shared__ int cur[256];
  __shared__ uint32_t sbuf[DCAP];
  int b = blockIdx.x;
  int t = threadIdx.x;

  // ---- phase 1: per-(block,bucket) histogram ----
  if (b < nb) {
    lh[t] = 0;
    __syncthreads();
    int base = b * EPBH;
#pragma unroll
    for (int j = 0; j < 32; ++j) {
      int e = base + j * 256 + t;
      if (e < ne) {
        int d = __builtin_nontemporal_load(&dst[e]);
        atomicAdd(&lh[d >> 8], 1);
      }
    }
    __syncthreads();
    if (t < nbuck) hist[(size_t)t * nb + b] = lh[t];
  }
  __threadfence();
  grid.sync();

  // ---- phase 2a: block b scans bucket b's row (over blocks), in place ----
  if (b < nbuck) {
    int v = (t < nb) ? hist[(size_t)b * nb + t] : 0;
    ls[t] = v;
    __syncthreads();
    for (int off = 1; off < 256; off <<= 1) {
      int x = (t >= off) ? ls[t - off] : 0;
      __syncthreads();
      ls[t] += x;
      __syncthreads();
    }
    if (t < nb) hist[(size_t)b * nb + t] = ls[t] - v;  // exclusive within bucket
    if (t == 255) bt[b] = ls[255];                     // bucket total
  }
  __threadfence();
  grid.sync();

  // ---- phase 2b: block 0 scans bucket totals -> bko ----
  if (b == 0) {
    int v = (t < nbuck) ? bt[t] : 0;
    ls[t] = v;
    __syncthreads();
    for (int off = 1; off < 256; off <<= 1) {
      int x = (t >= off) ? ls[t - off] : 0;
      __syncthreads();
      ls[t] += x;
      __syncthreads();
    }
    if (t < nbuck) bko[t] = ls[t] - v;
    if (t == 0) bko[nbuck] = ne;
  }
  __threadfence();
  grid.sync();

  // ---- phase 3: scatter packed edge records, LDS-scope cursors ----
  if (b < nb) {
    if (t < nbuck) cur[t] = hist[(size_t)t * nb + b] + bko[t];
    __syncthreads();
    int base = b * EPBH;
#pragma unroll
    for (int j = 0; j < 32; ++j) {
      int e = base + j * 256 + t;
      if (e < ne) {
        int s = __builtin_nontemporal_load(&src[e]);
        int d = __builtin_nontemporal_load(&dst[e]);
        int pos = atomicAdd(&cur[d >> 8], 1);   // LDS-scope
        ebuf[pos] = ((uint32_t)s << 8) | (uint32_t)(d & 255);
      }
    }
  }
  __threadfence();
  grid.sync();

  // ---- phase 4: block b builds bucket b's exact CSR slice + dinv in LDS ----
  if (b < nbuck) {
    int start = bko[b];
    int end = bko[b + 1];
    lh[t] = 0;                 // lcnt
    __syncthreads();
    for (int k = start + t; k < end; k += 256) {
      uint32_t ed = ebuf[k];
      int rel = k - start;
      if (rel < DCAP) sbuf[rel] = ed;
      atomicAdd(&lh[ed & 255u], 1);             // LDS-scope
    }
    __syncthreads();
    int v = lh[t];
    ls[t] = v;                 // lofs
    __syncthreads();
    for (int off = 1; off < 256; off <<= 1) {
      int x = (t >= off) ? ls[t - off] : 0;
      __syncthreads();
      ls[t] += x;
      __syncthreads();
    }
    int excl = ls[t] - v;
    int node = b * 256 + t;
    if (node < n) {
      row_ptr[node] = start + excl;
      dinv[node] = rsqrtf((float)(v + 1));      // +1 self-loop
    }
    cur[t] = start + excl;
    __syncthreads();
    for (int k = start + t; k < end; k += 256) {
      int rel = k - start;
      uint32_t ed = (rel < DCAP) ? sbuf[rel] : ebuf[k];
      int pos = atomicAdd(&cur[ed & 255u], 1);  // LDS-scope
      col[pos] = (int)(ed >> 8);
    }
    if (b == 0 && t == 0) row_ptr[n] = ne;
  }
}

// ---------------- MFMA fp16 GEMM fused with dinv pre-scale (R12, proven) ----------------
// v_mfma_f32_16x16x32_f16: A/B frag = 8 f16/lane (k = (lane>>4)*8 + i);
// C/D: col = lane&15, row = (lane>>4)*4 + reg  [m89-verified, dtype-indep].
// LDS rows padded to 136 halfs -> ds_read_b128 2-way bank-aliased (free).

typedef _Float16 half_t;
typedef __attribute__((ext_vector_type(8))) _Float16 f16x8;
typedef __attribute__((ext_vector_type(4))) float f32x4;

#define LDP 136

__device__ __forceinline__ void gemm_core(half_t (*As)[LDP], half_t (*Bs)[LDP],
                                          const float* __restrict__ dinv,
                                          __half* __restrict__ out,
                                          int row0, int nrows, int tid) {
  int wv = tid >> 6;                // wave -> rows wv*16
  int lane = tid & 63;
  int m = lane & 15;
  int kg = lane >> 4;               // 0..3

  f32x4 acc[8];
#pragma unroll
  for (int ct = 0; ct < 8; ++ct) acc[ct] = (f32x4){0.f, 0.f, 0.f, 0.f};

#pragma unroll
  for (int ks = 0; ks < 4; ++ks) {  // K = 4 x 32
    f16x8 a = *(const f16x8*)&As[wv * 16 + m][ks * 32 + kg * 8];
#pragma unroll
    for (int ct = 0; ct < 8; ++ct) {
      f16x8 b = *(const f16x8*)&Bs[ct * 16 + m][ks * 32 + kg * 8];
      acc[ct] = __builtin_amdgcn_mfma_f32_16x16x32_f16(a, b, acc[ct], 0, 0, 0);
    }
  }

  int orow = row0 + wv * 16 + kg * 4;
  float d0 = (orow + 0 < nrows) ? dinv[orow + 0] : 0.f;
  float d1 = (orow + 1 < nrows) ? dinv[orow + 1] : 0.f;
  float d2 = (orow + 2 < nrows) ? dinv[orow + 2] : 0.f;
  float d3 = (orow + 3 < nrows) ? dinv[orow + 3] : 0.f;
#pragma unroll
  for (int ct = 0; ct < 8; ++ct) {
    int ocol = ct * 16 + m;
    if (orow + 0 < nrows) out[(size_t)(orow + 0) * 128 + ocol] = __float2half_rn(acc[ct][0] * d0);
    if (orow + 1 < nrows) out[(size_t)(orow + 1) * 128 + ocol] = __float2half_rn(acc[ct][1] * d1);
    if (orow + 2 < nrows) out[(size_t)(orow + 2) * 128 + ocol] = __float2half_rn(acc[ct][2] * d2);
    if (orow + 3 < nrows) out[(size_t)(orow + 3) * 128 + ocol] = __float2half_rn(acc[ct][3] * d3);
  }
}

__device__ __forceinline__ void stage_W(half_t (*Bs)[LDP], const float* __restrict__ W, int tid) {
#pragma unroll
  for (int it = 0; it < 16; ++it) {
    int idx = it * 256 + tid;       // 0..4095
    int k = idx >> 5;               // 0..127
    int f4 = (idx & 31) * 4;        // 0..124
    float4 w = *(const float4*)&W[(size_t)k * 128 + f4];
    Bs[f4 + 0][k] = (half_t)w.x;
    Bs[f4 + 1][k] = (half_t)w.y;
    Bs[f4 + 2][k] = (half_t)w.z;
    Bs[f4 + 3][k] = (half_t)w.w;
  }
}

__global__ __launch_bounds__(256) void gemm_mfma_f32in(const float* __restrict__ in,
                                                       const float* __restrict__ W,
                                                       const float* __restrict__ dinv,
                                                       __half* __restrict__ out, int nrows) {
  __shared__ half_t As[64][LDP];
  __shared__ half_t Bs[128][LDP];
  int tid = threadIdx.x;
  int row0 = blockIdx.x * 64;
  stage_W(Bs, W, tid);
#pragma unroll
  for (int it = 0; it < 8; ++it) {
    int idx = it * 256 + tid;       // 0..2047
    int r = idx >> 5;
    int k4 = (idx & 31) * 4;
    int grow = row0 + r;
    float4 v = make_float4(0.f, 0.f, 0.f, 0.f);
    if (grow < nrows) v = *(const float4*)&in[(size_t)grow * 128 + k4];
    As[r][k4 + 0] = (half_t)v.x;
    As[r][k4 + 1] = (half_t)v.y;
    As[r][k4 + 2] = (half_t)v.z;
    As[r][k4 + 3] = (half_t)v.w;
  }
  __syncthreads();
  gemm_core(As, Bs, dinv, out, row0, nrows, tid);
}

__global__ __launch_bounds__(256) void gemm_mfma_f16in(const __half* __restrict__ in,
                                                       const float* __restrict__ W,
                                                       const float* __restrict__ dinv,
                                                       __half* __restrict__ out, int nrows) {
  __shared__ half_t As[64][LDP];
  __shared__ half_t Bs[128][LDP];
  int tid = threadIdx.x;
  int row0 = blockIdx.x * 64;
  stage_W(Bs, W, tid);
  // uint4 = 16 B = 8 halfs per (r,k8) slot (R11 bug was uint2 here).
#pragma unroll
  for (int it = 0; it < 4; ++it) {
    int idx = it * 256 + tid;       // 0..1023
    int r = idx >> 4;               // 0..63
    int k8 = (idx & 15) * 8;        // 0..120
    int grow = row0 + r;
    uint4 v = make_uint4(0u, 0u, 0u, 0u);
    if (grow < nrows) v = *(const uint4*)&in[(size_t)grow * 128 + k8];
    *(uint4*)&As[r][k8] = v;
  }
  __syncthreads();
  gemm_core(As, Bs, dinv, out, row0, nrows, tid);
}

// ---------------- fp16 row gather helpers ----------------

__device__ inline float4 h4_to_f4(uint2 u) {
  __half2 a = *(__half2*)&u.x;
  __half2 b = *(__half2*)&u.y;
  float2 fa = __half22float2(a);
  float2 fb = __half22float2(b);
  return make_float4(fa.x, fa.y, fb.x, fb.y);
}

// ---------------- Aggregation (R7, proven): 1 node/wave, half-wave = 256B fp16 row ----------------

__global__ __launch_bounds__(256) void aggregate_h(const __half* __restrict__ hsh,
                                                   const int* __restrict__ row_ptr,
                                                   const int* __restrict__ col,
                                                   const float* __restrict__ dinv,
                                                   const float* __restrict__ bias,
                                                   __half* __restrict__ out, int n) {
  int node = (blockIdx.x * blockDim.x + threadIdx.x) >> 6;
  if (node >= n) return;
  int lane = threadIdx.x & 63;
  int half_ = lane >> 5;
  int f4 = lane & 31;
  const uint2* rows = (const uint2*)hsh;  // row stride = 32 uint2

  int start = row_ptr[node];
  int end = row_ptr[node + 1];

  float4 acc = make_float4(0.f, 0.f, 0.f, 0.f);
  if (half_ == 0) acc = h4_to_f4(rows[(size_t)node * 32 + f4]);  // self-loop

  int e = start + half_;
  for (; e + 14 < end; e += 16) {
    uint2 u[8];
#pragma unroll
    for (int j = 0; j < 8; ++j) u[j] = rows[(size_t)col[e + 2 * j] * 32 + f4];
#pragma unroll
    for (int j = 0; j < 8; ++j) {
      float4 v = h4_to_f4(u[j]);
      acc.x += v.x; acc.y += v.y; acc.z += v.z; acc.w += v.w;
    }
  }
  for (; e < end; e += 2) {
    float4 v = h4_to_f4(rows[(size_t)col[e] * 32 + f4]);
    acc.x += v.x; acc.y += v.y; acc.z += v.z; acc.w += v.w;
  }

  acc.x += __shfl_xor(acc.x, 32);
  acc.y += __shfl_xor(acc.y, 32);
  acc.z += __shfl_xor(acc.z, 32);
  acc.w += __shfl_xor(acc.w, 32);

  if (half_ == 0) {
    float d = dinv[node];
    float4 b = ((const float4*)bias)[f4];
    __half2 h01 = __floats2half2_rn(fmaxf(acc.x * d + b.x, 0.f), fmaxf(acc.y * d + b.y, 0.f));
    __half2 h23 = __floats2half2_rn(fmaxf(acc.z * d + b.z, 0.f), fmaxf(acc.w * d + b.w, 0.f));
    uint2 o = make_uint2(*(uint*)&h01, *(uint*)&h23);
    ((uint2*)out)[(size_t)node * 32 + f4] = o;
  }
}

// Layer-2 variant: same gather, fused 128->1 projection with Wc, fp32 out.

__global__ __launch_bounds__(256) void aggregate_dot_h(const __half* __restrict__ hsh,
                                                       const int* __restrict__ row_ptr,
                                                       const int* __restrict__ col,
                                                       const float* __restrict__ dinv,
                                                       const float* __restrict__ bias,
                                                       const float* __restrict__ Wc,
                                                       const float* __restrict__ bc,
                                                       float* __restrict__ out, int n) {
  int node = (blockIdx.x * blockDim.x + threadIdx.x) >> 6;
  if (node >= n) return;
  int lane = threadIdx.x & 63;
  int half_ = lane >> 5;
  int f4 = lane & 31;
  const uint2* rows = (const uint2*)hsh;

  int start = row_ptr[node];
  int end = row_ptr[node + 1];

  float4 acc = make_float4(0.f, 0.f, 0.f, 0.f);
  if (half_ == 0) acc = h4_to_f4(rows[(size_t)node * 32 + f4]);  // self-loop

  int e = start + half_;
  for (; e + 14 < end; e += 16) {
    uint2 u[8];
#pragma unroll
    for (int j = 0; j < 8; ++j) u[j] = rows[(size_t)col[e + 2 * j] * 32 + f4];
#pragma unroll
    for (int j = 0; j < 8; ++j) {
      float4 v = h4_to_f4(u[j]);
      acc.x += v.x; acc.y += v.y; acc.z += v.z; acc.w += v.w;
    }
  }
  for (; e < end; e += 2) {
    float4 v = h4_to_f4(rows[(size_t)col[e] * 32 + f4]);
    acc.x += v.x; acc.y += v.y; acc.z += v.z; acc.w += v.w;
  }

  acc.x += __shfl_xor(acc.x, 32);
  acc.y += __shfl_xor(acc.y, 32);
  acc.z += __shfl_xor(acc.z, 32);
  acc.w += __shfl_xor(acc.w, 32);

  float d = dinv[node];
  float4 b = ((const float4*)bias)[f4];
  float4 w = ((const float4*)Wc)[f4];
  float s = fmaxf(acc.x * d + b.x, 0.f) * w.x
          + fmaxf(acc.y * d + b.y, 0.f) * w.y
          + fmaxf(acc.z * d + b.z, 0.f) * w.z
          + fmaxf(acc.w * d + b.w, 0.f) * w.w;
#pragma unroll
  for (int off = 16; off; off >>= 1) s += __shfl_xor(s, off);
  if (lane == 0) out[node] = s + bc[0];
}

// ---------------- launch ----------------

extern "C" void kernel_launch(void* const* d_in, const int* in_sizes, int n_in,
                              void* d_out, int out_size, void* d_ws, size_t ws_size,
                              hipStream_t stream) {
  const float* x  = (const float*)d_in[0];
  const int* ei   = (const int*)d_in[1];
  const float* W1 = (const float*)d_in[2];
  const float* b1 = (const float*)d_in[3];
  const float* W2 = (const float*)d_in[4];
  const float* b2 = (const float*)d_in[5];
  const float* Wc = (const float*)d_in[6];
  const float* bc = (const float*)d_in[7];
  float* out = (float*)d_out;

  int n  = in_sizes[0] / 128;
  int ne = in_sizes[1] / 2;
  const int* src = ei;
  const int* dst = ei + ne;

  int NBb = (ne + EPBH - 1) / EPBH;      // 196 hist/scatter blocks
  int NBUCK = (n + 255) >> 8;            // 196 buckets (requires n <= 65536)
  int HN = NBUCK * NBb;

  char* p = (char*)d_ws;
  auto alloc = [&](size_t bytes) {
    char* r = p;
    p += (bytes + 255) & ~(size_t)255;
    return r;
  };
  int*    hist    = (int*)alloc((size_t)HN * 4);
  int*    bt      = (int*)alloc(256 * 4);
  int*    bko     = (int*)alloc(260 * 4);
  int*    row_ptr = (int*)alloc((size_t)(n + 1) * 4);
  float*  dinv    = (float*)alloc((size_t)n * 4);
  int*    col     = (int*)alloc((size_t)ne * 4);
  __half* hsh     = (__half*)alloc((size_t)n * 128 * 2);  // fp16 GEMM output
  __half* h1      = (__half*)alloc((size_t)n * 128 * 2);  // fp16 layer-1 output
  uint32_t* ebuf  = (uint32_t*)alloc((size_t)ne * 4);     // packed edge records

  int gblocks = NBb > NBUCK ? NBb : NBUCK;  // 196
  void* cargs[] = {(void*)&src, (void*)&dst, (void*)&hist, (void*)&bt, (void*)&bko,
                   (void*)&row_ptr, (void*)&dinv, (void*)&col, (void*)&ebuf,
                   (void*)&ne, (void*)&NBb, (void*)&NBUCK, (void*)&n};
  hipLaunchCooperativeKernel((const void*)build_csr_coop, dim3(gblocks), dim3(256),
                             cargs, 0, stream);

  int gemm_blocks = (n + 63) / 64;
  int agg_blocks = (n + 3) / 4;  // 4 waves/block, 1 wave/node

  gemm_mfma_f32in<<<gemm_blocks, 256, 0, stream>>>(x, W1, dinv, hsh, n);
  aggregate_h<<<agg_blocks, 256, 0, stream>>>(hsh, row_ptr, col, dinv, b1, h1, n);
  gemm_mfma_f16in<<<gemm_blocks, 256, 0, stream>>>(h1, W2, dinv, hsh, n);
  aggregate_dot_h<<<agg_blocks, 256, 0, stream>>>(hsh, row_ptr, col, dinv, b2, Wc, bc, out, n);
}

// Round 14
// 253.074 us; speedup vs baseline: 1.6467x; 1.6467x over previous
//
#include <hip/hip_runtime.h>
#include <hip/hip_fp16.h>
#include <cstdint>

// ---------------- CSR build: 3-dispatch bucketed counting sort (R14) ----------------
// R13 lesson: cooperative grid.sync serialized the whole build at 9% occupancy
// (233us) -- kernel boundaries beat grid-wide sync on MI355X. R14: keep
// separate kernels but drop both scan dispatches; scatter/csr blocks derive
// offsets redundantly from the hist matrix (196-entry row sums + LDS scan of
// bucket totals, L2-resident, ~1-2us) -- deterministic, atomic-free.

#define EPBH 8192   // edges per block in hist/scatter passes (256 thr x 32)
#define DCAP 9216   // LDS staging capacity in bucket_csr (mean ~8163 edges)

__global__ __launch_bounds__(256) void bucket_hist(const int* __restrict__ dst,
                                                   int* __restrict__ hist,
                                                   int ne, int nb, int nbuck) {
  __shared__ int lh[256];
  lh[threadIdx.x] = 0;
  __syncthreads();
  int base = blockIdx.x * EPBH;
#pragma unroll
  for (int j = 0; j < 32; ++j) {
    int e = base + j * 256 + threadIdx.x;
    if (e < ne) {
      int d = __builtin_nontemporal_load(&dst[e]);
      atomicAdd(&lh[d >> 8], 1);
    }
  }
  __syncthreads();
  if (threadIdx.x < nbuck)
    hist[(size_t)threadIdx.x * nb + blockIdx.x] = lh[threadIdx.x];
}

// Scatter: block computes its own cursors from hist (no scan kernels).
// cur[t] = bko[t] + sum_{b'<b} hist[t][b'], bko = excl-scan of bucket totals.
__global__ __launch_bounds__(256) void bucket_scatter(const int* __restrict__ src,
                                                      const int* __restrict__ dst,
                                                      const int* __restrict__ hist,
                                                      uint32_t* __restrict__ ebuf,
                                                      int ne, int nb, int nbuck) {
  __shared__ int ls[256];
  __shared__ int cur[256];
  int t = threadIdx.x;
  int b = blockIdx.x;
  int pref = 0, tot = 0;
  if (t < nbuck) {
    const int* row = &hist[(size_t)t * nb];
    for (int b2 = 0; b2 < nb; ++b2) {
      int h = row[b2];
      tot += h;
      if (b2 < b) pref += h;
    }
  }
  ls[t] = (t < nbuck) ? tot : 0;
  __syncthreads();
  for (int off = 1; off < 256; off <<= 1) {
    int x = (t >= off) ? ls[t - off] : 0;
    __syncthreads();
    ls[t] += x;
    __syncthreads();
  }
  if (t < nbuck) cur[t] = (ls[t] - tot) + pref;   // bko[t] + block prefix
  __syncthreads();
  int base = b * EPBH;
#pragma unroll
  for (int j = 0; j < 32; ++j) {
    int e = base + j * 256 + t;
    if (e < ne) {
      int s = __builtin_nontemporal_load(&src[e]);
      int d = __builtin_nontemporal_load(&dst[e]);
      int pos = atomicAdd(&cur[d >> 8], 1);   // LDS-scope
      ebuf[pos] = ((uint32_t)s << 8) | (uint32_t)(d & 255);
    }
  }
}

// One block per bucket: derive bko locally, then exact CSR slice + dinv in LDS.
__global__ __launch_bounds__(256) void bucket_csr(const uint32_t* __restrict__ ebuf,
                                                  const int* __restrict__ hist,
                                                  int* __restrict__ row_ptr,
                                                  float* __restrict__ dinv,
                                                  int* __restrict__ col,
                                                  int ne, int nb, int nbuck, int n) {
  __shared__ int lh[256];
  __shared__ int ls[256];
  __shared__ int cur[256];
  __shared__ int bko_l[257];
  __shared__ uint32_t sbuf[DCAP];
  int t = threadIdx.x;
  int b = blockIdx.x;
  int tot = 0;
  if (t < nbuck) {
    const int* row = &hist[(size_t)t * nb];
    for (int b2 = 0; b2 < nb; ++b2) tot += row[b2];
  }
  ls[t] = (t < nbuck) ? tot : 0;
  __syncthreads();
  for (int off = 1; off < 256; off <<= 1) {
    int x = (t >= off) ? ls[t - off] : 0;
    __syncthreads();
    ls[t] += x;
    __syncthreads();
  }
  bko_l[t] = ls[t] - tot;                      // exclusive bucket offsets
  if (t == 0) bko_l[256] = ne;
  __syncthreads();
  int start = bko_l[b];
  int end = (b + 1 < nbuck) ? bko_l[b + 1] : ne;

  lh[t] = 0;
  __syncthreads();
  for (int k = start + t; k < end; k += 256) {
    uint32_t ed = ebuf[k];
    int rel = k - start;
    if (rel < DCAP) sbuf[rel] = ed;
    atomicAdd(&lh[ed & 255u], 1);              // LDS-scope
  }
  __syncthreads();
  int v = lh[t];
  ls[t] = v;
  __syncthreads();
  for (int off = 1; off < 256; off <<= 1) {
    int x = (t >= off) ? ls[t - off] : 0;
    __syncthreads();
    ls[t] += x;
    __syncthreads();
  }
  int excl = ls[t] - v;
  int node = b * 256 + t;
  if (node < n) {
    row_ptr[node] = start + excl;
    dinv[node] = rsqrtf((float)(v + 1));       // +1 self-loop
  }
  cur[t] = start + excl;
  __syncthreads();
  for (int k = start + t; k < end; k += 256) {
    int rel = k - start;
    uint32_t ed = (rel < DCAP) ? sbuf[rel] : ebuf[k];
    int pos = atomicAdd(&cur[ed & 255u], 1);   // LDS-scope
    col[pos] = (int)(ed >> 8);
  }
  if (b == nbuck - 1 && t == 0) row_ptr[n] = ne;
}

// ---------------- MFMA fp16 GEMM fused with dinv pre-scale (R12, proven) ----------------
// v_mfma_f32_16x16x32_f16: A/B frag = 8 f16/lane (k = (lane>>4)*8 + i);
// C/D: col = lane&15, row = (lane>>4)*4 + reg  [m89-verified, dtype-indep].
// LDS rows padded to 136 halfs -> ds_read_b128 2-way bank-aliased (free).

typedef _Float16 half_t;
typedef __attribute__((ext_vector_type(8))) _Float16 f16x8;
typedef __attribute__((ext_vector_type(4))) float f32x4;

#define LDP 136

__device__ __forceinline__ void gemm_core(half_t (*As)[LDP], half_t (*Bs)[LDP],
                                          const float* __restrict__ dinv,
                                          __half* __restrict__ out,
                                          int row0, int nrows, int tid) {
  int wv = tid >> 6;                // wave -> rows wv*16
  int lane = tid & 63;
  int m = lane & 15;
  int kg = lane >> 4;               // 0..3

  f32x4 acc[8];
#pragma unroll
  for (int ct = 0; ct < 8; ++ct) acc[ct] = (f32x4){0.f, 0.f, 0.f, 0.f};

#pragma unroll
  for (int ks = 0; ks < 4; ++ks) {  // K = 4 x 32
    f16x8 a = *(const f16x8*)&As[wv * 16 + m][ks * 32 + kg * 8];
#pragma unroll
    for (int ct = 0; ct < 8; ++ct) {
      f16x8 b = *(const f16x8*)&Bs[ct * 16 + m][ks * 32 + kg * 8];
      acc[ct] = __builtin_amdgcn_mfma_f32_16x16x32_f16(a, b, acc[ct], 0, 0, 0);
    }
  }

  int orow = row0 + wv * 16 + kg * 4;
  float d0 = (orow + 0 < nrows) ? dinv[orow + 0] : 0.f;
  float d1 = (orow + 1 < nrows) ? dinv[orow + 1] : 0.f;
  float d2 = (orow + 2 < nrows) ? dinv[orow + 2] : 0.f;
  float d3 = (orow + 3 < nrows) ? dinv[orow + 3] : 0.f;
#pragma unroll
  for (int ct = 0; ct < 8; ++ct) {
    int ocol = ct * 16 + m;
    if (orow + 0 < nrows) out[(size_t)(orow + 0) * 128 + ocol] = __float2half_rn(acc[ct][0] * d0);
    if (orow + 1 < nrows) out[(size_t)(orow + 1) * 128 + ocol] = __float2half_rn(acc[ct][1] * d1);
    if (orow + 2 < nrows) out[(size_t)(orow + 2) * 128 + ocol] = __float2half_rn(acc[ct][2] * d2);
    if (orow + 3 < nrows) out[(size_t)(orow + 3) * 128 + ocol] = __float2half_rn(acc[ct][3] * d3);
  }
}

__device__ __forceinline__ void stage_W(half_t (*Bs)[LDP], const float* __restrict__ W, int tid) {
#pragma unroll
  for (int it = 0; it < 16; ++it) {
    int idx = it * 256 + tid;       // 0..4095
    int k = idx >> 5;               // 0..127
    int f4 = (idx & 31) * 4;        // 0..124
    float4 w = *(const float4*)&W[(size_t)k * 128 + f4];
    Bs[f4 + 0][k] = (half_t)w.x;
    Bs[f4 + 1][k] = (half_t)w.y;
    Bs[f4 + 2][k] = (half_t)w.z;
    Bs[f4 + 3][k] = (half_t)w.w;
  }
}

__global__ __launch_bounds__(256) void gemm_mfma_f32in(const float* __restrict__ in,
                                                       const float* __restrict__ W,
                                                       const float* __restrict__ dinv,
                                                       __half* __restrict__ out, int nrows) {
  __shared__ half_t As[64][LDP];
  __shared__ half_t Bs[128][LDP];
  int tid = threadIdx.x;
  int row0 = blockIdx.x * 64;
  stage_W(Bs, W, tid);
#pragma unroll
  for (int it = 0; it < 8; ++it) {
    int idx = it * 256 + tid;       // 0..2047
    int r = idx >> 5;
    int k4 = (idx & 31) * 4;
    int grow = row0 + r;
    float4 v = make_float4(0.f, 0.f, 0.f, 0.f);
    if (grow < nrows) v = *(const float4*)&in[(size_t)grow * 128 + k4];
    As[r][k4 + 0] = (half_t)v.x;
    As[r][k4 + 1] = (half_t)v.y;
    As[r][k4 + 2] = (half_t)v.z;
    As[r][k4 + 3] = (half_t)v.w;
  }
  __syncthreads();
  gemm_core(As, Bs, dinv, out, row0, nrows, tid);
}

__global__ __launch_bounds__(256) void gemm_mfma_f16in(const __half* __restrict__ in,
                                                       const float* __restrict__ W,
                                                       const float* __restrict__ dinv,
                                                       __half* __restrict__ out, int nrows) {
  __shared__ half_t As[64][LDP];
  __shared__ half_t Bs[128][LDP];
  int tid = threadIdx.x;
  int row0 = blockIdx.x * 64;
  stage_W(Bs, W, tid);
  // uint4 = 16 B = 8 halfs per (r,k8) slot (R11 bug was uint2 here).
#pragma unroll
  for (int it = 0; it < 4; ++it) {
    int idx = it * 256 + tid;       // 0..1023
    int r = idx >> 4;               // 0..63
    int k8 = (idx & 15) * 8;        // 0..120
    int grow = row0 + r;
    uint4 v = make_uint4(0u, 0u, 0u, 0u);
    if (grow < nrows) v = *(const uint4*)&in[(size_t)grow * 128 + k8];
    *(uint4*)&As[r][k8] = v;
  }
  __syncthreads();
  gemm_core(As, Bs, dinv, out, row0, nrows, tid);
}

// ---------------- fp16 row gather helpers ----------------

__device__ inline float4 h4_to_f4(uint2 u) {
  __half2 a = *(__half2*)&u.x;
  __half2 b = *(__half2*)&u.y;
  float2 fa = __half22float2(a);
  float2 fb = __half22float2(b);
  return make_float4(fa.x, fa.y, fb.x, fb.y);
}

// ---------------- Aggregation (R7, proven): 1 node/wave, half-wave = 256B fp16 row ----------------

__global__ __launch_bounds__(256) void aggregate_h(const __half* __restrict__ hsh,
                                                   const int* __restrict__ row_ptr,
                                                   const int* __restrict__ col,
                                                   const float* __restrict__ dinv,
                                                   const float* __restrict__ bias,
                                                   __half* __restrict__ out, int n) {
  int node = (blockIdx.x * blockDim.x + threadIdx.x) >> 6;
  if (node >= n) return;
  int lane = threadIdx.x & 63;
  int half_ = lane >> 5;
  int f4 = lane & 31;
  const uint2* rows = (const uint2*)hsh;  // row stride = 32 uint2

  int start = row_ptr[node];
  int end = row_ptr[node + 1];

  float4 acc = make_float4(0.f, 0.f, 0.f, 0.f);
  if (half_ == 0) acc = h4_to_f4(rows[(size_t)node * 32 + f4]);  // self-loop

  int e = start + half_;
  for (; e + 14 < end; e += 16) {
    uint2 u[8];
#pragma unroll
    for (int j = 0; j < 8; ++j) u[j] = rows[(size_t)col[e + 2 * j] * 32 + f4];
#pragma unroll
    for (int j = 0; j < 8; ++j) {
      float4 v = h4_to_f4(u[j]);
      acc.x += v.x; acc.y += v.y; acc.z += v.z; acc.w += v.w;
    }
  }
  for (; e < end; e += 2) {
    float4 v = h4_to_f4(rows[(size_t)col[e] * 32 + f4]);
    acc.x += v.x; acc.y += v.y; acc.z += v.z; acc.w += v.w;
  }

  acc.x += __shfl_xor(acc.x, 32);
  acc.y += __shfl_xor(acc.y, 32);
  acc.z += __shfl_xor(acc.z, 32);
  acc.w += __shfl_xor(acc.w, 32);

  if (half_ == 0) {
    float d = dinv[node];
    float4 b = ((const float4*)bias)[f4];
    __half2 h01 = __floats2half2_rn(fmaxf(acc.x * d + b.x, 0.f), fmaxf(acc.y * d + b.y, 0.f));
    __half2 h23 = __floats2half2_rn(fmaxf(acc.z * d + b.z, 0.f), fmaxf(acc.w * d + b.w, 0.f));
    uint2 o = make_uint2(*(uint*)&h01, *(uint*)&h23);
    ((uint2*)out)[(size_t)node * 32 + f4] = o;
  }
}

// Layer-2 variant: same gather, fused 128->1 projection with Wc, fp32 out.

__global__ __launch_bounds__(256) void aggregate_dot_h(const __half* __restrict__ hsh,
                                                       const int* __restrict__ row_ptr,
                                                       const int* __restrict__ col,
                                                       const float* __restrict__ dinv,
                                                       const float* __restrict__ bias,
                                                       const float* __restrict__ Wc,
                                                       const float* __restrict__ bc,
                                                       float* __restrict__ out, int n) {
  int node = (blockIdx.x * blockDim.x + threadIdx.x) >> 6;
  if (node >= n) return;
  int lane = threadIdx.x & 63;
  int half_ = lane >> 5;
  int f4 = lane & 31;
  const uint2* rows = (const uint2*)hsh;

  int start = row_ptr[node];
  int end = row_ptr[node + 1];

  float4 acc = make_float4(0.f, 0.f, 0.f, 0.f);
  if (half_ == 0) acc = h4_to_f4(rows[(size_t)node * 32 + f4]);  // self-loop

  int e = start + half_;
  for (; e + 14 < end; e += 16) {
    uint2 u[8];
#pragma unroll
    for (int j = 0; j < 8; ++j) u[j] = rows[(size_t)col[e + 2 * j] * 32 + f4];
#pragma unroll
    for (int j = 0; j < 8; ++j) {
      float4 v = h4_to_f4(u[j]);
      acc.x += v.x; acc.y += v.y; acc.z += v.z; acc.w += v.w;
    }
  }
  for (; e < end; e += 2) {
    float4 v = h4_to_f4(rows[(size_t)col[e] * 32 + f4]);
    acc.x += v.x; acc.y += v.y; acc.z += v.z; acc.w += v.w;
  }

  acc.x += __shfl_xor(acc.x, 32);
  acc.y += __shfl_xor(acc.y, 32);
  acc.z += __shfl_xor(acc.z, 32);
  acc.w += __shfl_xor(acc.w, 32);

  float d = dinv[node];
  float4 b = ((const float4*)bias)[f4];
  float4 w = ((const float4*)Wc)[f4];
  float s = fmaxf(acc.x * d + b.x, 0.f) * w.x
          + fmaxf(acc.y * d + b.y, 0.f) * w.y
          + fmaxf(acc.z * d + b.z, 0.f) * w.z
          + fmaxf(acc.w * d + b.w, 0.f) * w.w;
#pragma unroll
  for (int off = 16; off; off >>= 1) s += __shfl_xor(s, off);
  if (lane == 0) out[node] = s + bc[0];
}

// ---------------- launch ----------------

extern "C" void kernel_launch(void* const* d_in, const int* in_sizes, int n_in,
                              void* d_out, int out_size, void* d_ws, size_t ws_size,
                              hipStream_t stream) {
  const float* x  = (const float*)d_in[0];
  const int* ei   = (const int*)d_in[1];
  const float* W1 = (const float*)d_in[2];
  const float* b1 = (const float*)d_in[3];
  const float* W2 = (const float*)d_in[4];
  const float* b2 = (const float*)d_in[5];
  const float* Wc = (const float*)d_in[6];
  const float* bc = (const float*)d_in[7];
  float* out = (float*)d_out;

  int n  = in_sizes[0] / 128;
  int ne = in_sizes[1] / 2;
  const int* src = ei;
  const int* dst = ei + ne;

  int NBb = (ne + EPBH - 1) / EPBH;      // 196 hist/scatter blocks
  int NBUCK = (n + 255) >> 8;            // 196 buckets (requires n <= 65536)
  int HN = NBUCK * NBb;

  char* p = (char*)d_ws;
  auto alloc = [&](size_t bytes) {
    char* r = p;
    p += (bytes + 255) & ~(size_t)255;
    return r;
  };
  int*    hist    = (int*)alloc((size_t)HN * 4);
  int*    row_ptr = (int*)alloc((size_t)(n + 1) * 4);
  float*  dinv    = (float*)alloc((size_t)n * 4);
  int*    col     = (int*)alloc((size_t)ne * 4);
  __half* hsh     = (__half*)alloc((size_t)n * 128 * 2);  // fp16 GEMM output
  __half* h1      = (__half*)alloc((size_t)n * 128 * 2);  // fp16 layer-1 output
  uint32_t* ebuf  = (uint32_t*)alloc((size_t)ne * 4);     // packed edge records

  bucket_hist<<<NBb, 256, 0, stream>>>(dst, hist, ne, NBb, NBUCK);
  bucket_scatter<<<NBb, 256, 0, stream>>>(src, dst, hist, ebuf, ne, NBb, NBUCK);
  bucket_csr<<<NBUCK, 256, 0, stream>>>(ebuf, hist, row_ptr, dinv, col, ne, NBb, NBUCK, n);

  int gemm_blocks = (n + 63) / 64;
  int agg_blocks = (n + 3) / 4;  // 4 waves/block, 1 wave/node

  gemm_mfma_f32in<<<gemm_blocks, 256, 0, stream>>>(x, W1, dinv, hsh, n);
  aggregate_h<<<agg_blocks, 256, 0, stream>>>(hsh, row_ptr, col, dinv, b1, h1, n);
  gemm_mfma_f16in<<<gemm_blocks, 256, 0, stream>>>(h1, W2, dinv, hsh, n);
  aggregate_dot_h<<<agg_blocks, 256, 0, stream>>>(hsh, row_ptr, col, dinv, b2, Wc, bc, out, n);
}

// Round 15
// 226.645 us; speedup vs baseline: 1.8387x; 1.1166x over previous
//
#include <hip/hip_runtime.h>
#include <hip/hip_fp16.h>
#include <cstdint>

// ---------------- CSR build: atomic-free bucketed counting sort (R7, proven) ----------------
// Best-measured configuration (R10, 226 us). R13 (coop-fused) and R14
// (scan-inlined) both regressed; kernel boundaries + tiny scan kernels win.

#define EPBH 4096   // edges per block in hist/scatter passes (256 thr x 16)
#define DCAP 9216   // LDS staging capacity in bucket_csr (mean ~8163 edges)

__global__ __launch_bounds__(256) void bucket_hist(const int* __restrict__ dst,
                                                   int* __restrict__ hist,
                                                   int ne, int nb, int nbuck) {
  __shared__ int lh[256];
  lh[threadIdx.x] = 0;
  __syncthreads();
  int base = blockIdx.x * EPBH;
#pragma unroll
  for (int j = 0; j < 16; ++j) {
    int e = base + j * 256 + threadIdx.x;
    if (e < ne) {
      int d = __builtin_nontemporal_load(&dst[e]);
      atomicAdd(&lh[d >> 8], 1);
    }
  }
  __syncthreads();
  if (threadIdx.x < nbuck)
    hist[(size_t)threadIdx.x * nb + blockIdx.x] = lh[threadIdx.x];
}

__global__ void scan_block(const int* __restrict__ in, int* __restrict__ part,
                           int* __restrict__ bsum, int n) {
  __shared__ int s[1024];
  int i = blockIdx.x * 1024 + threadIdx.x;
  int v = (i < n) ? in[i] : 0;
  s[threadIdx.x] = v;
  __syncthreads();
  for (int off = 1; off < 1024; off <<= 1) {
    int t = (threadIdx.x >= (unsigned)off) ? s[threadIdx.x - off] : 0;
    __syncthreads();
    s[threadIdx.x] += t;
    __syncthreads();
  }
  if (i < n) part[i] = s[threadIdx.x] - v;           // exclusive within block
  if (threadIdx.x == 1023) bsum[blockIdx.x] = s[1023];
}

__global__ void scan_partials(int* __restrict__ bsum, int nb) {  // nb <= 256
  __shared__ int s[256];
  int v = (threadIdx.x < (unsigned)nb) ? bsum[threadIdx.x] : 0;
  s[threadIdx.x] = v;
  __syncthreads();
  for (int off = 1; off < 256; off <<= 1) {
    int t = (threadIdx.x >= (unsigned)off) ? s[threadIdx.x - off] : 0;
    __syncthreads();
    s[threadIdx.x] += t;
    __syncthreads();
  }
  if (threadIdx.x < (unsigned)nb) bsum[threadIdx.x] = s[threadIdx.x] - v;
}

__global__ void finalize_scan(const int* __restrict__ part, const int* __restrict__ bsum,
                              int* __restrict__ out, int n) {
  int i = blockIdx.x * blockDim.x + threadIdx.x;
  if (i < n) out[i] = part[i] + bsum[i >> 10];
}

__global__ __launch_bounds__(256) void bucket_scatter(const int* __restrict__ src,
                                                      const int* __restrict__ dst,
                                                      const int* __restrict__ scanned,
                                                      uint2* __restrict__ ebuf,
                                                      int ne, int nb, int nbuck) {
  __shared__ int cur[256];
  if (threadIdx.x < nbuck)
    cur[threadIdx.x] = scanned[(size_t)threadIdx.x * nb + blockIdx.x];
  __syncthreads();
  int base = blockIdx.x * EPBH;
#pragma unroll
  for (int j = 0; j < 16; ++j) {
    int e = base + j * 256 + threadIdx.x;
    if (e < ne) {
      int s = __builtin_nontemporal_load(&src[e]);
      int d = __builtin_nontemporal_load(&dst[e]);
      int pos = atomicAdd(&cur[d >> 8], 1);   // LDS-scope
      ebuf[pos] = make_uint2((unsigned)s, (unsigned)d);
    }
  }
}

// One block per bucket: exact CSR slice + dinv, all in LDS.
__global__ __launch_bounds__(256) void bucket_csr(const uint2* __restrict__ ebuf,
                                                  const int* __restrict__ scanned,
                                                  int* __restrict__ row_ptr,
                                                  float* __restrict__ dinv,
                                                  int* __restrict__ col,
                                                  int ne, int nb, int nbuck, int n) {
  __shared__ int lcnt[256];
  __shared__ int lofs[256];
  __shared__ int cur[256];
  __shared__ uint2 sbuf[DCAP];
  int b = blockIdx.x;
  int start = scanned[(size_t)b * nb];
  int end = (b + 1 < nbuck) ? scanned[(size_t)(b + 1) * nb] : ne;
  lcnt[threadIdx.x] = 0;
  __syncthreads();
  for (int k = start + threadIdx.x; k < end; k += 256) {
    uint2 ed = ebuf[k];
    int rel = k - start;
    if (rel < DCAP) sbuf[rel] = ed;
    atomicAdd(&lcnt[ed.y & 255], 1);          // LDS-scope
  }
  __syncthreads();
  int v = lcnt[threadIdx.x];
  lofs[threadIdx.x] = v;
  __syncthreads();
  for (int off = 1; off < 256; off <<= 1) {
    int t = (threadIdx.x >= (unsigned)off) ? lofs[threadIdx.x - off] : 0;
    __syncthreads();
    lofs[threadIdx.x] += t;
    __syncthreads();
  }
  int excl = lofs[threadIdx.x] - v;
  int node = b * 256 + threadIdx.x;
  if (node < n) {
    row_ptr[node] = start + excl;
    dinv[node] = rsqrtf((float)(v + 1));      // +1 self-loop
  }
  cur[threadIdx.x] = start + excl;
  __syncthreads();
  for (int k = start + threadIdx.x; k < end; k += 256) {
    int rel = k - start;
    uint2 ed = (rel < DCAP) ? sbuf[rel] : ebuf[k];
    int pos = atomicAdd(&cur[ed.y & 255], 1); // LDS-scope
    col[pos] = (int)ed.x;
  }
  if (b == nbuck - 1 && threadIdx.x == 0) row_ptr[n] = ne;
}

// ---------------- MFMA fp16 GEMM fused with dinv pre-scale ----------------
// v_mfma_f32_16x16x32_f16: A/B frag = 8 f16/lane (k = (lane>>4)*8 + i);
// C/D: col = lane&15, row = (lane>>4)*4 + reg  [m89-verified, dtype-indep].
// LDS rows padded to 136 halfs -> ds_read_b128 2-way bank-aliased (free).

typedef _Float16 half_t;
typedef __attribute__((ext_vector_type(8))) _Float16 f16x8;
typedef __attribute__((ext_vector_type(4))) float f32x4;

#define LDP 136

__global__ __launch_bounds__(256) void gemm_mfma_h(const float* __restrict__ in,
                                                   const float* __restrict__ W,
                                                   const float* __restrict__ dinv,
                                                   __half* __restrict__ out, int nrows) {
  __shared__ half_t As[64][LDP];    // A tile: 64 rows x 128 k
  __shared__ half_t Bs[128][LDP];   // W^T: Bs[f][k]
  int tid = threadIdx.x;
  int row0 = blockIdx.x * 64;

  // stage W^T (fp32 -> fp16): 128x128, 16 float4 per thread
#pragma unroll
  for (int it = 0; it < 16; ++it) {
    int idx = it * 256 + tid;       // 0..4095
    int k = idx >> 5;               // 0..127
    int f4 = (idx & 31) * 4;        // 0..124
    float4 w = *(const float4*)&W[(size_t)k * 128 + f4];
    Bs[f4 + 0][k] = (half_t)w.x;
    Bs[f4 + 1][k] = (half_t)w.y;
    Bs[f4 + 2][k] = (half_t)w.z;
    Bs[f4 + 3][k] = (half_t)w.w;
  }
  // stage A (fp32 -> fp16): 64 rows x 128 k, 8 float4 per thread
#pragma unroll
  for (int it = 0; it < 8; ++it) {
    int idx = it * 256 + tid;       // 0..2047
    int r = idx >> 5;
    int k4 = (idx & 31) * 4;
    int grow = row0 + r;
    float4 v = make_float4(0.f, 0.f, 0.f, 0.f);
    if (grow < nrows) v = *(const float4*)&in[(size_t)grow * 128 + k4];
    As[r][k4 + 0] = (half_t)v.x;
    As[r][k4 + 1] = (half_t)v.y;
    As[r][k4 + 2] = (half_t)v.z;
    As[r][k4 + 3] = (half_t)v.w;
  }
  __syncthreads();

  int wv = tid >> 6;                // wave -> rows wv*16
  int lane = tid & 63;
  int m = lane & 15;
  int kg = lane >> 4;               // 0..3

  f32x4 acc[8];
#pragma unroll
  for (int ct = 0; ct < 8; ++ct) acc[ct] = (f32x4){0.f, 0.f, 0.f, 0.f};

#pragma unroll
  for (int ks = 0; ks < 4; ++ks) {  // K = 4 x 32
    f16x8 a = *(const f16x8*)&As[wv * 16 + m][ks * 32 + kg * 8];
#pragma unroll
    for (int ct = 0; ct < 8; ++ct) {
      f16x8 b = *(const f16x8*)&Bs[ct * 16 + m][ks * 32 + kg * 8];
      acc[ct] = __builtin_amdgcn_mfma_f32_16x16x32_f16(a, b, acc[ct], 0, 0, 0);
    }
  }

  int orow = row0 + wv * 16 + kg * 4;
  float d0 = (orow + 0 < nrows) ? dinv[orow + 0] : 0.f;
  float d1 = (orow + 1 < nrows) ? dinv[orow + 1] : 0.f;
  float d2 = (orow + 2 < nrows) ? dinv[orow + 2] : 0.f;
  float d3 = (orow + 3 < nrows) ? dinv[orow + 3] : 0.f;
#pragma unroll
  for (int ct = 0; ct < 8; ++ct) {
    int ocol = ct * 16 + m;
    if (orow + 0 < nrows) out[(size_t)(orow + 0) * 128 + ocol] = __float2half_rn(acc[ct][0] * d0);
    if (orow + 1 < nrows) out[(size_t)(orow + 1) * 128 + ocol] = __float2half_rn(acc[ct][1] * d1);
    if (orow + 2 < nrows) out[(size_t)(orow + 2) * 128 + ocol] = __float2half_rn(acc[ct][2] * d2);
    if (orow + 3 < nrows) out[(size_t)(orow + 3) * 128 + ocol] = __float2half_rn(acc[ct][3] * d3);
  }
}

// ---------------- fp16 row gather helpers ----------------

__device__ inline float4 h4_to_f4(uint2 u) {
  __half2 a = *(__half2*)&u.x;
  __half2 b = *(__half2*)&u.y;
  float2 fa = __half22float2(a);
  float2 fb = __half22float2(b);
  return make_float4(fa.x, fa.y, fb.x, fb.y);
}

// ---------------- Aggregation (R7, proven): 1 node/wave, half-wave = 256B fp16 row ----------------
// 16 edges / 4 KB outstanding per wave (R3/R9 lesson: maximize bytes in flight).

__global__ __launch_bounds__(256) void aggregate_h(const __half* __restrict__ hsh,
                                                   const int* __restrict__ row_ptr,
                                                   const int* __restrict__ col,
                                                   const float* __restrict__ dinv,
                                                   const float* __restrict__ bias,
                                                   float* __restrict__ out, int n) {
  int node = (blockIdx.x * blockDim.x + threadIdx.x) >> 6;
  if (node >= n) return;
  int lane = threadIdx.x & 63;
  int half_ = lane >> 5;
  int f4 = lane & 31;
  const uint2* rows = (const uint2*)hsh;  // row stride = 32 uint2

  int start = row_ptr[node];
  int end = row_ptr[node + 1];

  float4 acc = make_float4(0.f, 0.f, 0.f, 0.f);
  if (half_ == 0) acc = h4_to_f4(rows[(size_t)node * 32 + f4]);  // self-loop

  int e = start + half_;
  for (; e + 14 < end; e += 16) {
    uint2 u[8];
#pragma unroll
    for (int j = 0; j < 8; ++j) u[j] = rows[(size_t)col[e + 2 * j] * 32 + f4];
#pragma unroll
    for (int j = 0; j < 8; ++j) {
      float4 v = h4_to_f4(u[j]);
      acc.x += v.x; acc.y += v.y; acc.z += v.z; acc.w += v.w;
    }
  }
  for (; e < end; e += 2) {
    float4 v = h4_to_f4(rows[(size_t)col[e] * 32 + f4]);
    acc.x += v.x; acc.y += v.y; acc.z += v.z; acc.w += v.w;
  }

  acc.x += __shfl_xor(acc.x, 32);
  acc.y += __shfl_xor(acc.y, 32);
  acc.z += __shfl_xor(acc.z, 32);
  acc.w += __shfl_xor(acc.w, 32);

  if (half_ == 0) {
    float d = dinv[node];
    float4 b = ((const float4*)bias)[f4];
    float4 o;
    o.x = fmaxf(acc.x * d + b.x, 0.f);
    o.y = fmaxf(acc.y * d + b.y, 0.f);
    o.z = fmaxf(acc.z * d + b.z, 0.f);
    o.w = fmaxf(acc.w * d + b.w, 0.f);
    ((float4*)out)[(size_t)node * 32 + f4] = o;
  }
}

// Layer-2 variant: same gather, fused 128->1 projection with Wc.

__global__ __launch_bounds__(256) void aggregate_dot_h(const __half* __restrict__ hsh,
                                                       const int* __restrict__ row_ptr,
                                                       const int* __restrict__ col,
                                                       const float* __restrict__ dinv,
                                                       const float* __restrict__ bias,
                                                       const float* __restrict__ Wc,
                                                       const float* __restrict__ bc,
                                                       float* __restrict__ out, int n) {
  int node = (blockIdx.x * blockDim.x + threadIdx.x) >> 6;
  if (node >= n) return;
  int lane = threadIdx.x & 63;
  int half_ = lane >> 5;
  int f4 = lane & 31;
  const uint2* rows = (const uint2*)hsh;

  int start = row_ptr[node];
  int end = row_ptr[node + 1];

  float4 acc = make_float4(0.f, 0.f, 0.f, 0.f);
  if (half_ == 0) acc = h4_to_f4(rows[(size_t)node * 32 + f4]);  // self-loop

  int e = start + half_;
  for (; e + 14 < end; e += 16) {
    uint2 u[8];
#pragma unroll
    for (int j = 0; j < 8; ++j) u[j] = rows[(size_t)col[e + 2 * j] * 32 + f4];
#pragma unroll
    for (int j = 0; j < 8; ++j) {
      float4 v = h4_to_f4(u[j]);
      acc.x += v.x; acc.y += v.y; acc.z += v.z; acc.w += v.w;
    }
  }
  for (; e < end; e += 2) {
    float4 v = h4_to_f4(rows[(size_t)col[e] * 32 + f4]);
    acc.x += v.x; acc.y += v.y; acc.z += v.z; acc.w += v.w;
  }

  acc.x += __shfl_xor(acc.x, 32);
  acc.y += __shfl_xor(acc.y, 32);
  acc.z += __shfl_xor(acc.z, 32);
  acc.w += __shfl_xor(acc.w, 32);

  float d = dinv[node];
  float4 b = ((const float4*)bias)[f4];
  float4 w = ((const float4*)Wc)[f4];
  float s = fmaxf(acc.x * d + b.x, 0.f) * w.x
          + fmaxf(acc.y * d + b.y, 0.f) * w.y
          + fmaxf(acc.z * d + b.z, 0.f) * w.z
          + fmaxf(acc.w * d + b.w, 0.f) * w.w;
#pragma unroll
  for (int off = 16; off; off >>= 1) s += __shfl_xor(s, off);
  if (lane == 0) out[node] = s + bc[0];
}

// ---------------- launch ----------------

extern "C" void kernel_launch(void* const* d_in, const int* in_sizes, int n_in,
                              void* d_out, int out_size, void* d_ws, size_t ws_size,
                              hipStream_t stream) {
  const float* x  = (const float*)d_in[0];
  const int* ei   = (const int*)d_in[1];
  const float* W1 = (const float*)d_in[2];
  const float* b1 = (const float*)d_in[3];
  const float* W2 = (const float*)d_in[4];
  const float* b2 = (const float*)d_in[5];
  const float* Wc = (const float*)d_in[6];
  const float* bc = (const float*)d_in[7];
  float* out = (float*)d_out;

  int n  = in_sizes[0] / 128;
  int ne = in_sizes[1] / 2;
  const int* src = ei;
  const int* dst = ei + ne;

  int NBb = (ne + EPBH - 1) / EPBH;      // 391 hist/scatter blocks
  int NBUCK = (n + 255) >> 8;            // 196 buckets (requires n <= 65536)
  int HN = NBUCK * NBb;                  // 76,636 hist entries

  char* p = (char*)d_ws;
  auto alloc = [&](size_t bytes) {
    char* r = p;
    p += (bytes + 255) & ~(size_t)255;
    return r;
  };
  int*    hist    = (int*)alloc((size_t)HN * 4);
  int*    part    = (int*)alloc((size_t)HN * 4);
  int*    bsum    = (int*)alloc(256 * 4);
  int*    row_ptr = (int*)alloc((size_t)(n + 1) * 4);
  float*  dinv    = (float*)alloc((size_t)n * 4);
  int*    col     = (int*)alloc((size_t)ne * 4);
  __half* hsh     = (__half*)alloc((size_t)n * 128 * 2);  // fp16 GEMM output
  float*  h1      = (float*)alloc((size_t)n * 128 * 4);   // fp32 layer-1 output
  // ebuf aliases h1: ebuf (ne*8 = 12.8 MB <= 25.6 MB) is dead after
  // bucket_csr; h1 first written by aggregate_h, strictly later on stream.
  uint2*  ebuf    = (uint2*)h1;

  bucket_hist<<<NBb, 256, 0, stream>>>(dst, hist, ne, NBb, NBUCK);
  int nsb = (HN + 1023) / 1024;          // 75 <= 256
  scan_block<<<nsb, 1024, 0, stream>>>(hist, part, bsum, HN);
  scan_partials<<<1, 256, 0, stream>>>(bsum, nsb);
  finalize_scan<<<(HN + 255) / 256, 256, 0, stream>>>(part, bsum, hist, HN);
  bucket_scatter<<<NBb, 256, 0, stream>>>(src, dst, hist, ebuf, ne, NBb, NBUCK);
  bucket_csr<<<NBUCK, 256, 0, stream>>>(ebuf, hist, row_ptr, dinv, col, ne, NBb, NBUCK, n);

  int gemm_blocks = (n + 63) / 64;
  int agg_blocks = (n + 3) / 4;  // 4 waves/block, 1 wave/node

  gemm_mfma_h<<<gemm_blocks, 256, 0, stream>>>(x, W1, dinv, hsh, n);
  aggregate_h<<<agg_blocks, 256, 0, stream>>>(hsh, row_ptr, col, dinv, b1, h1, n);
  gemm_mfma_h<<<gemm_blocks, 256, 0, stream>>>(h1, W2, dinv, hsh, n);
  aggregate_dot_h<<<agg_blocks, 256, 0, stream>>>(hsh, row_ptr, col, dinv, b2, Wc, bc, out, n);
}